// Round 14
// baseline (216.603 us; speedup 1.0000x reference)
//
#include <hip/hip_runtime.h>
#include <math.h>

// Problem constants
#define BB 8
#define SS 1024
#define DD 512
#define HH 4
#define HD 128
#define N_SC (BB*HH*SS*SS)              // 2^25 score elements

// Rank-histogram: linear bins over |s| <= 0.625 (7 sigma for 128-dim cosines).
// v13: S buffer stores enc = (bin<<1)|sign; binning happens once on raw fp32.
// v14: per-block LDS histograms are merged into 64 global uint partials via
// skip-zero atomics in scores_hist's epilogue — reduce1 is eliminated
// (-16MB write, -16MB read, -1 launch). Counts remain bit-exact.
#define NB 8192
#define BINS 13107.2f                   // NB / 0.625
#define NBLK 2048                       // scores blocks
#define NP2 64                          // global partial histograms (= slices)

// Workspace layout (bytes)
#define OFF_S     0                                  // ushort enc [bh][q][k]  67 MB
#define SZ_S      ((size_t)N_SC*2)
#define OFF_QN    (OFF_S + SZ_S)                     // bf16 normalized Q [bh][s][128]
#define SZ_QN     ((size_t)BB*SS*DD*2)               // 8388608
#define OFF_KN    (OFF_QN + SZ_QN)
#define OFF_VT    (OFF_KN + SZ_QN)                   // bf16 V^T [bh][d=128][s=1024]
#define OFF_PARTS (OFF_VT + SZ_QN)                   // (unused since v14)
#define SZ_PARTS  ((size_t)NBLK*(NB/4)*4)            // 16777216
#define OFF_WMAG  (OFF_PARTS + SZ_PARTS)             // ushort bf16 wmag[NB]
#define OFF_PART2 (OFF_WMAG + (size_t)NB*2)          // uint[NP2][NB] atomic partials
#define OFF_CNT   (OFF_PART2 + (size_t)NP2*NB*4)     // uint[NB] final counts

typedef __bf16 bf16x8 __attribute__((ext_vector_type(8)));
typedef float  f32x4  __attribute__((ext_vector_type(4)));
typedef unsigned short ushort_t;

__device__ __forceinline__ unsigned bf16rne(float x) {   // RNE fp32->bf16 bits
  unsigned b = __float_as_uint(x);
  return (b + 0x7FFFu + ((b >> 16) & 1u)) >> 16;
}
__device__ __forceinline__ unsigned sbin(float s) {
  return (unsigned)fminf(fabsf(s)*BINS, 8191.0f);
}

// ---------------------------------------------------------------------------
// prep_vt v14: blocks [0,8192): normalize Q,K rows (v11 verified float4 path).
// blocks [8192,9216): V -> bf16 V^T. blocks [9216,9280): zero part2 (2MB)
// so scores_hist can atomically accumulate into it (stream order guarantees
// completion before scores_hist starts).
__global__ __launch_bounds__(256) void prep_vt_kernel(
    const float* __restrict__ q, const float* __restrict__ k,
    const float* __restrict__ v,
    unsigned* __restrict__ qn, unsigned* __restrict__ kn,
    unsigned* __restrict__ vt, unsigned* __restrict__ part2) {
  __shared__ float T[64][65];
  int t = threadIdx.x;
  if (blockIdx.x < 8192) {
    int lane = t & 31;
    int row = blockIdx.x*8 + (t >> 5);          // 0..65535
    const float* src; unsigned* dst; int r;
    if (row < 32768) { src = q; dst = qn; r = row; }
    else             { src = k; dst = kn; r = row - 32768; }
    int b = r >> 12, s = (r >> 2) & 1023, h = r & 3;
    float4 vv = *(const float4*)(src + ((size_t)(b*1024 + s))*512 + h*128 + lane*4);
    float sum = vv.x*vv.x + vv.y*vv.y + vv.z*vv.z + vv.w*vv.w;
    #pragma unroll
    for (int off = 16; off; off >>= 1) sum += __shfl_xor(sum, off, 64);  // stays in 32-half
    float inv = rsqrtf(sum);
    unsigned u0 = bf16rne(vv.x*inv) | (bf16rne(vv.y*inv) << 16);
    unsigned u1 = bf16rne(vv.z*inv) | (bf16rne(vv.w*inv) << 16);
    uint2 o = {u0, u1};
    *(uint2*)&dst[(size_t)((b*4 + h)*1024 + s)*64 + lane*2] = o;
  } else if (blockIdx.x < 9216) {
    int vb = blockIdx.x - 8192;                 // 0..1023
    int s0 = (vb & 15)*64, d0 = ((vb >> 4) & 1)*64, bh = vb >> 5;
    int b = bh >> 2, h = bh & 3;
    #pragma unroll
    for (int i = 0; i < 16; i++) {
      int idx = t + i*256, rs = idx >> 6, cd = idx & 63;
      T[rs][cd] = v[((size_t)(b*1024 + s0 + rs))*512 + h*128 + d0 + cd];
    }
    __syncthreads();
    #pragma unroll
    for (int i = 0; i < 8; i++) {
      int idx = t + i*256, rd = idx >> 5, c2 = (idx & 31)*2;
      unsigned u = bf16rne(T[c2][rd]) | (bf16rne(T[c2+1][rd]) << 16);
      vt[(size_t)(bh*128 + d0 + rd)*512 + (s0 + c2)/2] = u;
    }
  } else {
    int zb = blockIdx.x - 9216;                 // 0..63: zero part2[zb*NB ..+NB)
    uint4 z = {0u, 0u, 0u, 0u};
    #pragma unroll
    for (int i = 0; i < 8; i++)
      ((uint4*)part2)[(size_t)zb*(NB/4) + t + i*256] = z;
  }
}

// ---------------------------------------------------------------------------
// scores_hist v14: v12/v13 compute (two-pass K-split staging, raw-fp32 bin,
// enc store) unchanged. Writeback: instead of dumping the byte-packed LDS
// histogram to a per-block parts row (16MB traffic + reduce1 pass), unpack
// and atomicAdd only NONZERO byte-counts into global partial (L&63) —
// ~2-3K sparse atomics/block, 32 blocks/slice contention.
__global__ __launch_bounds__(256) void scores_hist_kernel(
    const ushort_t* __restrict__ qn, const ushort_t* __restrict__ kn,
    ushort_t* __restrict__ S, unsigned* __restrict__ part2) {
  __shared__ ushort_t Qs[128*64];      // 16 KB (one K-half)
  __shared__ ushort_t Ks[128*64];      // 16 KB
  __shared__ unsigned h8[NB/4];        // 8 KB byte-packed histogram
  int t = threadIdx.x;
  int L = blockIdx.x;                  // 0..2047
  int bh = L & 31, tile = L >> 5;
  int sq0 = (tile >> 3)*128, sk0 = (tile & 7)*128;

  #pragma unroll
  for (int i = 0; i < 8; i++) h8[t + i*256] = 0;

  const uint4* qg = (const uint4*)qn + (size_t)(bh*1024 + sq0)*16;
  const uint4* kg = (const uint4*)kn + (size_t)(bh*1024 + sk0)*16;

  int w = t >> 6, lane = t & 63, m16 = lane & 15, q2 = lane >> 4;
  int wm = (w >> 1)*64, wn = (w & 1)*64;
  f32x4 acc[4][4];
  #pragma unroll
  for (int i = 0; i < 4; i++)
    #pragma unroll
    for (int j = 0; j < 4; j++) acc[i][j] = (f32x4){0.f,0.f,0.f,0.f};

  #pragma unroll
  for (int kh2 = 0; kh2 < 2; kh2++) {
    // stage K-half kh2: 1024 uint4 -> Qs, 1024 uint4 -> Ks (32KB), swizzled
    #pragma unroll
    for (int i = 0; i < 4; i++) {
      int idx = t + i*256;             // 0..1023
      int r = idx >> 3, g = idx & 7;
      *(uint4*)&Qs[r*64 + (g ^ (r & 7))*8] = qg[r*16 + kh2*8 + g];
    }
    #pragma unroll
    for (int i = 0; i < 4; i++) {
      int idx = t + i*256;             // 0..1023
      int r = idx >> 3, g = idx & 7;
      *(uint4*)&Ks[r*64 + (g ^ (r & 7))*8] = kg[r*16 + kh2*8 + g];
    }
    __syncthreads();                   // half-tiles ready (h8 init on kh2=0)

    #pragma unroll
    for (int ks2 = 0; ks2 < 2; ks2++) {
      bf16x8 a[4], bb[4];
      #pragma unroll
      for (int i = 0; i < 4; i++) {
        int r = wm + i*16 + m16;
        a[i] = *(const bf16x8*)&Qs[r*64 + ((ks2*4 + q2) ^ (r & 7))*8];
      }
      #pragma unroll
      for (int j = 0; j < 4; j++) {
        int r = wn + j*16 + m16;
        bb[j] = *(const bf16x8*)&Ks[r*64 + ((ks2*4 + q2) ^ (r & 7))*8];
      }
      #pragma unroll
      for (int i = 0; i < 4; i++)
        #pragma unroll
        for (int j = 0; j < 4; j++)
          acc[i][j] = __builtin_amdgcn_mfma_f32_16x16x32_bf16(a[i], bb[j], acc[i][j], 0, 0, 0);
    }
    __syncthreads();                   // reads done before restage
  }

  // epilogue: bin raw fp32, store enc = (bin<<1)|sign, histogram atomic
  size_t Sbase = (size_t)bh << 20;
  #pragma unroll
  for (int i = 0; i < 4; i++)
    #pragma unroll
    for (int p = 0; p < 4; p++) {
      int row = sq0 + wm + i*16 + q2*4 + p;
      #pragma unroll
      for (int j = 0; j < 4; j++) {
        int col = sk0 + wn + j*16 + m16;
        float s = acc[i][j][p];
        unsigned bin = sbin(s);
        unsigned enc = (bin << 1) | (s < 0.f ? 1u : 0u);
        S[Sbase + ((size_t)row << 10) + col] = (ushort_t)enc;
        atomicAdd(&h8[bin >> 2], 1u << ((bin & 3)*8));
      }
    }
  __syncthreads();

  // v14 writeback: skip-zero global atomics into partial histogram L&63
  unsigned* dst = part2 + (size_t)(L & 63)*NB;
  #pragma unroll
  for (int i = 0; i < 8; i++) {
    unsigned wd = h8[t + i*256];
    if (wd) {
      int base = (t + i*256)*4;
      unsigned c0 = wd & 0xFFu, c1 = (wd >> 8) & 0xFFu;
      unsigned c2 = (wd >> 16) & 0xFFu, c3 = wd >> 24;
      if (c0) atomicAdd(&dst[base + 0], c0);
      if (c1) atomicAdd(&dst[base + 1], c1);
      if (c2) atomicAdd(&dst[base + 2], c2);
      if (c3) atomicAdd(&dst[base + 3], c3);
    }
  }
}

// ---------------------------------------------------------------------------
// reduce2: grid 32 x 256 thr. counts[bin] = sum over NP2 partials.
__global__ __launch_bounds__(256) void reduce2_kernel(
    const unsigned* __restrict__ parts2, unsigned* __restrict__ counts) {
  int g = blockIdx.x*256 + threadIdx.x;       // 0..8191 bin
  unsigned s = 0;
  #pragma unroll 8
  for (int p = 0; p < NP2; p++) s += parts2[(size_t)p*NB + g];
  counts[g] = s;
}

// ---------------------------------------------------------------------------
// scan: single block; read 32KB counts, prefix-scan, emit bf16 wmag.
// wmag[b] = -log((n - P_inc[b] + 0.5*(cnt[b]+1))/n)
__global__ __launch_bounds__(1024) void scan_kernel(
    const unsigned* __restrict__ counts, ushort_t* __restrict__ wmag) {
  __shared__ unsigned d[1024];
  int t = threadIdx.x;
  uint4 a  = ((const uint4*)counts)[t*2];
  uint4 b2 = ((const uint4*)counts)[t*2 + 1];
  unsigned loc[8] = {a.x, a.y, a.z, a.w, b2.x, b2.y, b2.z, b2.w};
  unsigned tot = 0;
  #pragma unroll
  for (int j = 0; j < 8; j++) tot += loc[j];
  d[t] = tot; __syncthreads();
  for (int off = 1; off < 1024; off <<= 1) {
    unsigned x = (t >= off) ? d[t - off] : 0u;
    __syncthreads();
    d[t] += x;
    __syncthreads();
  }
  unsigned run = d[t] - tot;            // exclusive prefix
  const float inv_n = 1.0f / (float)N_SC;
  #pragma unroll
  for (int j = 0; j < 8; j++) {
    run += loc[j];
    float rm = (float)(N_SC - run) + 0.5f*(float)(loc[j] + 1u);
    wmag[t*8 + j] = (ushort_t)bf16rne(-logf(rm * inv_n));
  }
}

// ---------------------------------------------------------------------------
// out (v13 VERIFIED, unchanged): O = W(S) @ V with enc-format S; A-frag
// weight is a direct lookup w = Wl[enc>>1] | ((enc&1)<<15).
__global__ __launch_bounds__(512) void out_kernel(
    const ushort_t* __restrict__ S, const ushort_t* __restrict__ wmag,
    const ushort_t* __restrict__ vt, float* __restrict__ out) {
  __shared__ ushort_t Buf[128*128 + 64*128];  // 48KB: Vs [128][128], Ss [64][128]
  __shared__ ushort_t Wl[NB];                 // 16 KB bf16 wmag table
  ushort_t* Vs = Buf;
  ushort_t* Ss = Buf + 128*128;
  int t = threadIdx.x;
  int L = blockIdx.x;                  // 0..511
  int bh = L & 31, q0 = (L >> 5)*64;
  int b = bh >> 2, h = bh & 3;

  #pragma unroll
  for (int i = 0; i < 2; i++)
    ((uint4*)Wl)[t + i*512] = ((const uint4*)wmag)[t + i*512];

  int w = t >> 6, lane = t & 63, m16 = lane & 15, q2 = lane >> 4;
  int qt = w & 3, kh = w >> 2;         // q-tile (4), k-half of chunk (2)
  int qw = q0 + qt*16;                 // wave's 16 q-rows
  const uint4* vg = (const uint4*)vt + (size_t)bh*128*128;   // [d=128][128 uint4]
  const uint4* sg = (const uint4*)S + (size_t)bh*1024*128;   // [q=1024][128 uint4]

  f32x4 oacc[8];
  #pragma unroll
  for (int j = 0; j < 8; j++) oacc[j] = (f32x4){0.f,0.f,0.f,0.f};

  for (int kc = 0; kc < 8; kc++) {
    #pragma unroll
    for (int i = 0; i < 4; i++) {
      int idx = t + i*512, row = idx >> 4, g = idx & 15;
      *(uint4*)&Vs[row*128 + (g ^ (row & 15))*8] = vg[row*128 + kc*16 + g];
    }
    #pragma unroll
    for (int i = 0; i < 2; i++) {
      int idx = t + i*512, row = idx >> 4, g = idx & 15;
      *(uint4*)&Ss[row*128 + (g ^ (row & 15))*8] = sg[(size_t)(q0 + row)*128 + kc*16 + g];
    }
    __syncthreads();                   // B1: Vs+Ss ready (Wl too on kc=0)

    #pragma unroll
    for (int u = 0; u < 2; u++) {
      int gk = kh*8 + u*4 + q2;        // 16B k-group within chunk (0..15)
      uint4 sv = *(const uint4*)&Ss[(qt*16 + m16)*128 + (gk ^ m16)*8];
      unsigned sc[4] = {sv.x, sv.y, sv.z, sv.w};
      union { bf16x8 v; unsigned u2[4]; } af;
      #pragma unroll
      for (int m = 0; m < 4; m++) {
        unsigned elo = sc[m] & 0xFFFFu;
        unsigned ehi = sc[m] >> 16;
        unsigned wlo = (unsigned)Wl[elo >> 1] | ((elo & 1u) << 15);
        unsigned whi = (unsigned)Wl[ehi >> 1] | ((ehi & 1u) << 15);
        af.u2[m] = wlo | (whi << 16);
      }
      #pragma unroll
      for (int j = 0; j < 8; j++) {
        bf16x8 bb = *(const bf16x8*)&Vs[(j*16 + m16)*128 + (gk ^ m16)*8];
        oacc[j] = __builtin_amdgcn_mfma_f32_16x16x32_bf16(af.v, bb, oacc[j], 0, 0, 0);
      }
    }
    __syncthreads();                   // B2: all LDS reads done before re-stage
  }

  // cross-K reduce: kh=1 waves drop partials in R (overlay on dead Buf)
  float* R = (float*)Buf;
  if (kh == 1) {
    #pragma unroll
    for (int j = 0; j < 8; j++)
      #pragma unroll
      for (int p = 0; p < 4; p++)
        R[(qt*16 + q2*4 + p)*129 + j*16 + m16] = oacc[j][p];
  }
  __syncthreads();
  if (kh == 0) {
    #pragma unroll
    for (int j = 0; j < 8; j++)
      #pragma unroll
      for (int p = 0; p < 4; p++)
        oacc[j][p] += R[(qt*16 + q2*4 + p)*129 + j*16 + m16];
    #pragma unroll
    for (int p = 0; p < 4; p++) {
      int qrow = qw + q2*4 + p;
      #pragma unroll
      for (int j = 0; j < 8; j++)
        out[(size_t)(b*1024 + qrow)*512 + h*128 + j*16 + m16] = oacc[j][p];
    }
  }
}

// ---------------------------------------------------------------------------
extern "C" void kernel_launch(void* const* d_in, const int* in_sizes, int n_in,
                              void* d_out, int out_size, void* d_ws, size_t ws_size,
                              hipStream_t stream) {
  const float* q = (const float*)d_in[0];
  const float* k = (const float*)d_in[1];
  const float* v = (const float*)d_in[2];
  float* out = (float*)d_out;
  char* ws = (char*)d_ws;

  ushort_t* Sbuf  = (ushort_t*)(ws + OFF_S);
  unsigned* qn    = (unsigned*)(ws + OFF_QN);
  unsigned* kn    = (unsigned*)(ws + OFF_KN);
  unsigned* vtb   = (unsigned*)(ws + OFF_VT);
  ushort_t* wmag  = (ushort_t*)(ws + OFF_WMAG);
  unsigned* part2 = (unsigned*)(ws + OFF_PART2);
  unsigned* cnt   = (unsigned*)(ws + OFF_CNT);

  hipLaunchKernelGGL(prep_vt_kernel, dim3(9280), dim3(256), 0, stream,
                     q, k, v, qn, kn, vtb, part2);
  hipLaunchKernelGGL(scores_hist_kernel, dim3(NBLK), dim3(256), 0, stream,
                     (const ushort_t*)qn, (const ushort_t*)kn, Sbuf, part2);
  hipLaunchKernelGGL(reduce2_kernel, dim3(32), dim3(256), 0, stream, part2, cnt);
  hipLaunchKernelGGL(scan_kernel, dim3(1), dim3(1024), 0, stream, cnt, wmag);
  hipLaunchKernelGGL(out_kernel, dim3(512), dim3(512), 0, stream,
                     (const ushort_t*)Sbuf, wmag, (const ushort_t*)vtb, out);
}